// Round 2
// baseline (402.621 us; speedup 1.0000x reference)
//
#include <hip/hip_runtime.h>

#define BN_EPS 1e-5f

// ---------------- degree / CSR construction ----------------

__global__ void count_deg_kernel(const int* __restrict__ col, int* __restrict__ cnt, int E) {
    int e = blockIdx.x * blockDim.x + threadIdx.x;
    if (e < E) atomicAdd(&cnt[col[e]], 1);
}

__global__ void dis_kernel(const int* __restrict__ cnt, float* __restrict__ dis, int N) {
    int i = blockIdx.x * blockDim.x + threadIdx.x;
    if (i < N) dis[i] = rsqrtf((float)(cnt[i] + 1));   // +1 self loop; always > 0
}

// single-block exclusive scan over N counts -> rowptr[0..N], cursor copy
__global__ __launch_bounds__(1024) void scan_kernel(const int* __restrict__ cnt,
                                                    int* __restrict__ rowptr,
                                                    int* __restrict__ cursor, int N) {
    __shared__ int sums[1024];
    int t = threadIdx.x;
    int per = (N + 1023) / 1024;
    int start = t * per;
    int local = 0;
    for (int i = 0; i < per; i++) {
        int idx = start + i;
        if (idx < N) local += cnt[idx];
    }
    sums[t] = local;
    __syncthreads();
    for (int off = 1; off < 1024; off <<= 1) {
        int v = (t >= off) ? sums[t - off] : 0;
        __syncthreads();
        sums[t] += v;
        __syncthreads();
    }
    int run = (t == 0) ? 0 : sums[t - 1];
    for (int i = 0; i < per; i++) {
        int idx = start + i;
        if (idx < N) {
            rowptr[idx] = run;
            cursor[idx] = run;
            run += cnt[idx];
        }
    }
    if (t == 0) rowptr[N] = sums[1023];
}

__global__ void scatter_kernel(const int* __restrict__ row, const int* __restrict__ col,
                               int* __restrict__ cursor, int* __restrict__ adj, int E) {
    int e = blockIdx.x * blockDim.x + threadIdx.x;
    if (e < E) {
        int pos = atomicAdd(&cursor[col[e]], 1);
        adj[pos] = row[e];
    }
}

// ---------------- GEMM: C[M,N] = A'[M,K] @ B[N,K]^T ----------------
// A' = A, or BN+ReLU(A) per-column (channel=k) when APPLY_BN.
// 64x64 tile, BK=16, 256 threads, 4x4 per thread.

template <bool APPLY_BN>
__global__ __launch_bounds__(256) void gemm_tn_kernel(
    const float* __restrict__ A,     // [M,K] row-major
    const float* __restrict__ B,     // [N,K] row-major
    const float* __restrict__ scale, // [K] (used if APPLY_BN)
    const float* __restrict__ shift, // [K]
    float* __restrict__ C,           // [M,N] row-major
    int M, int N, int K) {
    __shared__ float As[16][68];
    __shared__ float Bs[16][68];
    int tid = threadIdx.x;
    int m0 = blockIdx.y * 64;
    int n0 = blockIdx.x * 64;
    int lm = tid >> 2;         // 0..63
    int lk = (tid & 3) * 4;    // 0,4,8,12
    int ty = tid >> 4;         // 0..15
    int tx = tid & 15;         // 0..15

    float acc[4][4] = {};

    for (int k0 = 0; k0 < K; k0 += 16) {
        int am = m0 + lm;
        float4 av;
        if (am < M) {
            av = *(const float4*)(A + (size_t)am * K + k0 + lk);
        } else {
            av = make_float4(0.f, 0.f, 0.f, 0.f);
        }
        if (APPLY_BN) {
            av.x = fmaxf(fmaf(av.x, scale[k0 + lk + 0], shift[k0 + lk + 0]), 0.f);
            av.y = fmaxf(fmaf(av.y, scale[k0 + lk + 1], shift[k0 + lk + 1]), 0.f);
            av.z = fmaxf(fmaf(av.z, scale[k0 + lk + 2], shift[k0 + lk + 2]), 0.f);
            av.w = fmaxf(fmaf(av.w, scale[k0 + lk + 3], shift[k0 + lk + 3]), 0.f);
        }
        As[lk + 0][lm] = av.x;
        As[lk + 1][lm] = av.y;
        As[lk + 2][lm] = av.z;
        As[lk + 3][lm] = av.w;

        float4 bv = *(const float4*)(B + (size_t)(n0 + lm) * K + k0 + lk); // N % 64 == 0
        Bs[lk + 0][lm] = bv.x;
        Bs[lk + 1][lm] = bv.y;
        Bs[lk + 2][lm] = bv.z;
        Bs[lk + 3][lm] = bv.w;

        __syncthreads();
#pragma unroll
        for (int kk = 0; kk < 16; kk++) {
            float a[4], b[4];
#pragma unroll
            for (int i = 0; i < 4; i++) a[i] = As[kk][ty * 4 + i];
#pragma unroll
            for (int j = 0; j < 4; j++) b[j] = Bs[kk][tx * 4 + j];
#pragma unroll
            for (int i = 0; i < 4; i++)
#pragma unroll
                for (int j = 0; j < 4; j++) acc[i][j] = fmaf(a[i], b[j], acc[i][j]);
        }
        __syncthreads();
    }

#pragma unroll
    for (int i = 0; i < 4; i++) {
        int m = m0 + ty * 4 + i;
        if (m < M) {
            float* cp = C + (size_t)m * N + n0 + tx * 4;
#pragma unroll
            for (int j = 0; j < 4; j++) cp[j] = acc[i][j];
        }
    }
}

// ---------------- gather (CSR segment-sum with sym norm) ----------------
// h[v][c] = xl[v][c]*dis[v]^2 + sum_{r in adj(v)} xl[r][c]*dis[r]*dis[v]

template <int CPT> // channels per thread; IC = CPT*256
__global__ __launch_bounds__(256) void gather_kernel(
    const float* __restrict__ xl, const int* __restrict__ rowptr,
    const int* __restrict__ adj, const float* __restrict__ dis,
    float* __restrict__ h, int IC) {
    int v = blockIdx.x;
    float dv = dis[v];
    int c[CPT];
    float acc[CPT];
#pragma unroll
    for (int i = 0; i < CPT; i++) {
        c[i] = threadIdx.x + 256 * i;
        acc[i] = xl[(size_t)v * IC + c[i]] * dv * dv;
    }
    int e0 = rowptr[v], e1 = rowptr[v + 1];
    for (int e = e0; e < e1; e++) {
        int r = adj[e];
        float w = dis[r] * dv;
        const float* xr = xl + (size_t)r * IC;
#pragma unroll
        for (int i = 0; i < CPT; i++) acc[i] = fmaf(xr[c[i]], w, acc[i]);
    }
    float* hv = h + (size_t)v * IC;
#pragma unroll
    for (int i = 0; i < CPT; i++) hv[c[i]] = acc[i];
}

// ---------------- batchnorm stats (v2: float4 + block reduce) ----------------
// grid.x = row chunks; block = 256 threads; thread t handles channel-group
// g = t % (IC/4) (float4) and row-offset ro = t / (IC/4).

__global__ __launch_bounds__(256) void bn_stats_kernel(
    const float* __restrict__ h, float* __restrict__ sum, float* __restrict__ sumsq,
    int N, int IC, int rows_per_chunk) {
    int groups = IC >> 2;          // 128 (IC=512) or 64 (C=256)
    int rpi = 256 / groups;        // rows per iteration: 2 or 4
    int t = threadIdx.x;
    int g = t & (groups - 1);
    int ro = t / groups;
    int r0 = blockIdx.x * rows_per_chunk;
    int r1 = min(r0 + rows_per_chunk, N);

    float4 s = make_float4(0.f, 0.f, 0.f, 0.f);
    float4 q = make_float4(0.f, 0.f, 0.f, 0.f);
    for (int r = r0 + ro; r < r1; r += rpi) {
        float4 v = *(const float4*)(h + (size_t)r * IC + g * 4);
        s.x += v.x; s.y += v.y; s.z += v.z; s.w += v.w;
        q.x += v.x * v.x; q.y += v.y * v.y; q.z += v.z * v.z; q.w += v.w * v.w;
    }

    __shared__ float4 redS[256];
    __shared__ float4 redQ[256];
    redS[t] = s;
    redQ[t] = q;
    __syncthreads();
    if (ro == 0) {
        for (int i = 1; i < rpi; i++) {
            float4 o = redS[t + i * groups];
            s.x += o.x; s.y += o.y; s.z += o.z; s.w += o.w;
            float4 p = redQ[t + i * groups];
            q.x += p.x; q.y += p.y; q.z += p.z; q.w += p.w;
        }
        atomicAdd(&sum[4 * g + 0], s.x);
        atomicAdd(&sum[4 * g + 1], s.y);
        atomicAdd(&sum[4 * g + 2], s.z);
        atomicAdd(&sum[4 * g + 3], s.w);
        atomicAdd(&sumsq[4 * g + 0], q.x);
        atomicAdd(&sumsq[4 * g + 1], q.y);
        atomicAdd(&sumsq[4 * g + 2], q.z);
        atomicAdd(&sumsq[4 * g + 3], q.w);
    }
}

__global__ void bn_finalize_kernel(const float* __restrict__ sum, const float* __restrict__ sumsq,
                                   const float* __restrict__ gamma, const float* __restrict__ beta,
                                   float* __restrict__ scale, float* __restrict__ shift,
                                   int N, int IC) {
    int cc = blockIdx.x * blockDim.x + threadIdx.x;
    if (cc < IC) {
        float invN = 1.0f / (float)N;
        float mean = sum[cc] * invN;
        float var = sumsq[cc] * invN - mean * mean;
        float sc = gamma[cc] * rsqrtf(var + BN_EPS);
        scale[cc] = sc;
        shift[cc] = beta[cc] - mean * sc;
    }
}

// ---------------- final: out = relu(bn2(h2) + x) ----------------

__global__ void final_kernel(const float* __restrict__ h2, const float* __restrict__ x,
                             const float* __restrict__ scale, const float* __restrict__ shift,
                             float* __restrict__ out, int total4, int C4) {
    int idx = blockIdx.x * blockDim.x + threadIdx.x;
    if (idx >= total4) return;
    int c4 = (idx % C4) * 4;
    float4 h = ((const float4*)h2)[idx];
    float4 xv = ((const float4*)x)[idx];
    float4 o;
    o.x = fmaxf(fmaf(h.x, scale[c4 + 0], shift[c4 + 0]) + xv.x, 0.f);
    o.y = fmaxf(fmaf(h.y, scale[c4 + 1], shift[c4 + 1]) + xv.y, 0.f);
    o.z = fmaxf(fmaf(h.z, scale[c4 + 2], shift[c4 + 2]) + xv.z, 0.f);
    o.w = fmaxf(fmaf(h.w, scale[c4 + 3], shift[c4 + 3]) + xv.w, 0.f);
    ((float4*)out)[idx] = o;
}

// ---------------- launch ----------------

extern "C" void kernel_launch(void* const* d_in, const int* in_sizes, int n_in,
                              void* d_out, int out_size, void* d_ws, size_t ws_size,
                              hipStream_t stream) {
    const float* x  = (const float*)d_in[0];
    const int*   es = (const int*)d_in[1];
    const float* W1 = (const float*)d_in[2];
    const float* g1 = (const float*)d_in[3];
    const float* b1 = (const float*)d_in[4];
    const float* W2 = (const float*)d_in[5];
    const float* g2 = (const float*)d_in[6];
    const float* b2 = (const float*)d_in[7];
    float* out = (float*)d_out;

    const int E  = in_sizes[1] / 2;
    const int IC = in_sizes[3];   // 512
    const int C  = in_sizes[7];   // 256
    const int N  = in_sizes[0] / C;

    const int* row = es;
    const int* col = es + E;

    // ---- workspace layout ----
    char* w = (char*)d_ws;
    size_t off = 0;
    auto alloc = [&](size_t bytes) -> void* {
        void* p = w + off;
        off = (off + bytes + 255) & ~(size_t)255;
        return p;
    };
    int*   cnt     = (int*)alloc((size_t)N * 4);
    float* dis     = (float*)alloc((size_t)N * 4);
    int*   rowptr  = (int*)alloc((size_t)(N + 1) * 4);
    int*   cursor  = (int*)alloc((size_t)N * 4);
    int*   adj     = (int*)alloc((size_t)E * 4);
    float* bnbuf   = (float*)alloc((size_t)(2 * IC + 2 * C) * 4); // sum1,sumsq1,sum2,sumsq2
    float* sum1    = bnbuf;
    float* sumsq1  = bnbuf + IC;
    float* sum2    = bnbuf + 2 * IC;
    float* sumsq2  = bnbuf + 2 * IC + C;
    float* scale1  = (float*)alloc((size_t)IC * 4);
    float* shift1  = (float*)alloc((size_t)IC * 4);
    float* scale2  = (float*)alloc((size_t)C * 4);
    float* shift2  = (float*)alloc((size_t)C * 4);
    float* h1      = (float*)alloc((size_t)N * IC * 4);
    float* big     = (float*)alloc((size_t)N * IC * 4); // xl1; later xl2 + h2
    float* xl1 = big;
    float* xl2 = big;                      // alias: xl1 dead after gather1
    float* h2  = big + (size_t)N * C;      // distinct from xl2 region

    // ---- zero-init what needs it ----
    hipMemsetAsync(cnt, 0, (size_t)N * 4, stream);
    hipMemsetAsync(bnbuf, 0, (size_t)(2 * IC + 2 * C) * 4, stream);

    // ---- degree + CSR ----
    count_deg_kernel<<<(E + 255) / 256, 256, 0, stream>>>(col, cnt, E);
    dis_kernel<<<(N + 255) / 256, 256, 0, stream>>>(cnt, dis, N);
    scan_kernel<<<1, 1024, 0, stream>>>(cnt, rowptr, cursor, N);
    scatter_kernel<<<(E + 255) / 256, 256, 0, stream>>>(row, col, cursor, adj, E);

    // ---- layer 1 ----
    {
        dim3 grid(IC / 64, (N + 63) / 64);
        gemm_tn_kernel<false><<<grid, 256, 0, stream>>>(x, W1, nullptr, nullptr, xl1, N, IC, C);
    }
    gather_kernel<2><<<N, 256, 0, stream>>>(xl1, rowptr, adj, dis, h1, IC);
    {
        int chunks = 512;
        int rpc = (N + chunks - 1) / chunks;
        bn_stats_kernel<<<chunks, 256, 0, stream>>>(h1, sum1, sumsq1, N, IC, rpc);
    }
    bn_finalize_kernel<<<(IC + 255) / 256, 256, 0, stream>>>(sum1, sumsq1, g1, b1, scale1, shift1, N, IC);

    // ---- layer 2 (BN1+ReLU fused into GEMM2 A-load) ----
    {
        dim3 grid(C / 64, (N + 63) / 64);
        gemm_tn_kernel<true><<<grid, 256, 0, stream>>>(h1, W2, scale1, shift1, xl2, N, C, IC);
    }
    gather_kernel<1><<<N, 256, 0, stream>>>(xl2, rowptr, adj, dis, h2, C);
    {
        int chunks = 512;
        int rpc = (N + chunks - 1) / chunks;
        bn_stats_kernel<<<chunks, 256, 0, stream>>>(h2, sum2, sumsq2, N, C, rpc);
    }
    bn_finalize_kernel<<<(C + 255) / 256, 256, 0, stream>>>(sum2, sumsq2, g2, b2, scale2, shift2, N, C);

    // ---- epilogue: relu(bn2(h2) + x) ----
    {
        int total4 = (N * C) / 4;
        final_kernel<<<(total4 + 255) / 256, 256, 0, stream>>>(h2, x, scale2, shift2, out, total4, C / 4);
    }
}

// Round 3
// 348.791 us; speedup vs baseline: 1.1543x; 1.1543x over previous
//
#include <hip/hip_runtime.h>

#define BN_EPS 1e-5f

typedef __attribute__((ext_vector_type(8))) short short8;
typedef __attribute__((ext_vector_type(4))) float floatx4;

#define GLL(gp, lp)                                                            \
    __builtin_amdgcn_global_load_lds(                                          \
        (const __attribute__((address_space(1))) void*)(gp),                   \
        (__attribute__((address_space(3))) void*)(lp), 16, 0, 0)

__device__ inline unsigned short f2bf(float f) {
    unsigned int u = __float_as_uint(f);
    unsigned int r = (u + 0x7FFF + ((u >> 16) & 1)) >> 16;  // RNE
    return (unsigned short)r;
}

// ---------------- degree / CSR construction ----------------

__global__ void count_deg_kernel(const int* __restrict__ col, int* __restrict__ cnt, int E) {
    int e = blockIdx.x * blockDim.x + threadIdx.x;
    if (e < E) atomicAdd(&cnt[col[e]], 1);
}

__global__ void dis_kernel(const int* __restrict__ cnt, float* __restrict__ dis, int N) {
    int i = blockIdx.x * blockDim.x + threadIdx.x;
    if (i < N) dis[i] = rsqrtf((float)(cnt[i] + 1));   // +1 self loop; always > 0
}

__global__ __launch_bounds__(1024) void scan_kernel(const int* __restrict__ cnt,
                                                    int* __restrict__ rowptr,
                                                    int* __restrict__ cursor, int N) {
    __shared__ int sums[1024];
    int t = threadIdx.x;
    int per = (N + 1023) / 1024;
    int start = t * per;
    int local = 0;
    for (int i = 0; i < per; i++) {
        int idx = start + i;
        if (idx < N) local += cnt[idx];
    }
    sums[t] = local;
    __syncthreads();
    for (int off = 1; off < 1024; off <<= 1) {
        int v = (t >= off) ? sums[t - off] : 0;
        __syncthreads();
        sums[t] += v;
        __syncthreads();
    }
    int run = (t == 0) ? 0 : sums[t - 1];
    for (int i = 0; i < per; i++) {
        int idx = start + i;
        if (idx < N) {
            rowptr[idx] = run;
            cursor[idx] = run;
            run += cnt[idx];
        }
    }
    if (t == 0) rowptr[N] = sums[1023];
}

__global__ void scatter_kernel(const int* __restrict__ row, const int* __restrict__ col,
                               int* __restrict__ cursor, int* __restrict__ adj, int E) {
    int e = blockIdx.x * blockDim.x + threadIdx.x;
    if (e < E) {
        int pos = atomicAdd(&cursor[col[e]], 1);
        adj[pos] = row[e];
    }
}

// ---------------- fp32 -> bf16 conversion ----------------

__global__ void f2b_kernel(const float* __restrict__ in, ushort* __restrict__ out, int n4) {
    int i = blockIdx.x * blockDim.x + threadIdx.x;
    if (i < n4) {
        float4 v = ((const float4*)in)[i];
        ushort4 o;
        o.x = f2bf(v.x); o.y = f2bf(v.y); o.z = f2bf(v.z); o.w = f2bf(v.w);
        ((ushort4*)out)[i] = o;
    }
}

// BN+ReLU applied, then convert to bf16 (feeds GEMM2's A)
__global__ void bn_apply_b_kernel(const float* __restrict__ h,
                                  const float* __restrict__ scale,
                                  const float* __restrict__ shift,
                                  ushort* __restrict__ out, int n4, int IC4) {
    int i = blockIdx.x * blockDim.x + threadIdx.x;
    if (i >= n4) return;
    int c4 = (i & (IC4 - 1)) * 4;
    float4 v = ((const float4*)h)[i];
    ushort4 o;
    o.x = f2bf(fmaxf(fmaf(v.x, scale[c4 + 0], shift[c4 + 0]), 0.f));
    o.y = f2bf(fmaxf(fmaf(v.y, scale[c4 + 1], shift[c4 + 1]), 0.f));
    o.z = f2bf(fmaxf(fmaf(v.z, scale[c4 + 2], shift[c4 + 2]), 0.f));
    o.w = f2bf(fmaxf(fmaf(v.w, scale[c4 + 3], shift[c4 + 3]), 0.f));
    ((ushort4*)out)[i] = o;
}

// ---------------- MFMA GEMM: C[M,N] = A[M,K] @ B[N,K]^T (bf16 in, fp32 out) ---
// 128x128 tile, 4 waves each 64x64 via 4x4 of mfma_f32_16x16x32_bf16.
// global_load_lds width-16 staging; N % 128 == 0, K % 32 == 0.

__global__ __launch_bounds__(256) void gemm_mfma_kernel(
    const ushort* __restrict__ A, const ushort* __restrict__ B,
    float* __restrict__ C, int M, int N, int K) {
    __shared__ ushort As[128 * 32];
    __shared__ ushort Bs[128 * 32];
    int tid = threadIdx.x;
    int wave = tid >> 6;
    int lane = tid & 63;
    int quad = lane >> 4;
    int l15 = lane & 15;
    int m0 = blockIdx.y * 128;
    int n0 = blockIdx.x * 128;

    int srow = lane >> 2;        // row within 16-row chunk
    int skoff = (lane & 3) * 8;  // bf16-element offset within K-chunk

    floatx4 acc[4][4];
#pragma unroll
    for (int i = 0; i < 4; i++)
#pragma unroll
        for (int j = 0; j < 4; j++) acc[i][j] = (floatx4){0.f, 0.f, 0.f, 0.f};

    int wm = (wave & 1) * 64;
    int wn = (wave >> 1) * 64;

    for (int k0 = 0; k0 < K; k0 += 32) {
#pragma unroll
        for (int cc = 0; cc < 2; cc++) {
            int c = wave * 2 + cc;  // 16-row chunk index, 0..7
            int arow = m0 + c * 16 + srow;
            arow = min(arow, M - 1);
            const ushort* ga = A + (size_t)arow * K + k0 + skoff;
            GLL(ga, (char*)As + c * 1024);
            int brow = n0 + c * 16 + srow;
            const ushort* gb = B + (size_t)brow * K + k0 + skoff;
            GLL(gb, (char*)Bs + c * 1024);
        }
        __syncthreads();

        short8 af[4], bfr[4];
#pragma unroll
        for (int i = 0; i < 4; i++) {
            int r = wm + i * 16 + l15;
            af[i] = *(const short8*)(As + r * 32 + quad * 8);
        }
#pragma unroll
        for (int j = 0; j < 4; j++) {
            int r = wn + j * 16 + l15;
            bfr[j] = *(const short8*)(Bs + r * 32 + quad * 8);
        }
#pragma unroll
        for (int i = 0; i < 4; i++)
#pragma unroll
            for (int j = 0; j < 4; j++)
                acc[i][j] = __builtin_amdgcn_mfma_f32_16x16x32_bf16(af[i], bfr[j], acc[i][j], 0, 0, 0);
        __syncthreads();
    }

#pragma unroll
    for (int i = 0; i < 4; i++) {
#pragma unroll
        for (int r = 0; r < 4; r++) {
            int row = m0 + wm + i * 16 + quad * 4 + r;
            if (row < M) {
                float* cp = C + (size_t)row * N + n0 + wn + l15;
#pragma unroll
                for (int j = 0; j < 4; j++) cp[j * 16] = acc[i][j][r];
            }
        }
    }
}

// ---------------- gather (CSR segment-sum with sym norm) ----------------
// h[v][c] = xl[v][c]*dis[v]^2 + sum_{r in adj(v)} xl[r][c]*dis[r]*dis[v]

template <int CPT> // channels per thread; IC = CPT*256
__global__ __launch_bounds__(256) void gather_kernel(
    const float* __restrict__ xl, const int* __restrict__ rowptr,
    const int* __restrict__ adj, const float* __restrict__ dis,
    float* __restrict__ h, int IC) {
    int v = blockIdx.x;
    float dv = dis[v];
    int c[CPT];
    float acc[CPT];
#pragma unroll
    for (int i = 0; i < CPT; i++) {
        c[i] = threadIdx.x + 256 * i;
        acc[i] = xl[(size_t)v * IC + c[i]] * dv * dv;
    }
    int e0 = rowptr[v], e1 = rowptr[v + 1];
    for (int e = e0; e < e1; e++) {
        int r = adj[e];
        float w = dis[r] * dv;
        const float* xr = xl + (size_t)r * IC;
#pragma unroll
        for (int i = 0; i < CPT; i++) acc[i] = fmaf(xr[c[i]], w, acc[i]);
    }
    float* hv = h + (size_t)v * IC;
#pragma unroll
    for (int i = 0; i < CPT; i++) hv[c[i]] = acc[i];
}

// ---------------- batchnorm stats (float4 + block reduce) ----------------

__global__ __launch_bounds__(256) void bn_stats_kernel(
    const float* __restrict__ h, float* __restrict__ sum, float* __restrict__ sumsq,
    int N, int IC, int rows_per_chunk) {
    int groups = IC >> 2;          // 128 (IC=512) or 64 (C=256)
    int rpi = 256 / groups;        // rows per iteration: 2 or 4
    int t = threadIdx.x;
    int g = t & (groups - 1);
    int ro = t / groups;
    int r0 = blockIdx.x * rows_per_chunk;
    int r1 = min(r0 + rows_per_chunk, N);

    float4 s = make_float4(0.f, 0.f, 0.f, 0.f);
    float4 q = make_float4(0.f, 0.f, 0.f, 0.f);
    for (int r = r0 + ro; r < r1; r += rpi) {
        float4 v = *(const float4*)(h + (size_t)r * IC + g * 4);
        s.x += v.x; s.y += v.y; s.z += v.z; s.w += v.w;
        q.x += v.x * v.x; q.y += v.y * v.y; q.z += v.z * v.z; q.w += v.w * v.w;
    }

    __shared__ float4 redS[256];
    __shared__ float4 redQ[256];
    redS[t] = s;
    redQ[t] = q;
    __syncthreads();
    if (ro == 0) {
        for (int i = 1; i < rpi; i++) {
            float4 o = redS[t + i * groups];
            s.x += o.x; s.y += o.y; s.z += o.z; s.w += o.w;
            float4 p = redQ[t + i * groups];
            q.x += p.x; q.y += p.y; q.z += p.z; q.w += p.w;
        }
        atomicAdd(&sum[4 * g + 0], s.x);
        atomicAdd(&sum[4 * g + 1], s.y);
        atomicAdd(&sum[4 * g + 2], s.z);
        atomicAdd(&sum[4 * g + 3], s.w);
        atomicAdd(&sumsq[4 * g + 0], q.x);
        atomicAdd(&sumsq[4 * g + 1], q.y);
        atomicAdd(&sumsq[4 * g + 2], q.z);
        atomicAdd(&sumsq[4 * g + 3], q.w);
    }
}

__global__ void bn_finalize_kernel(const float* __restrict__ sum, const float* __restrict__ sumsq,
                                   const float* __restrict__ gamma, const float* __restrict__ beta,
                                   float* __restrict__ scale, float* __restrict__ shift,
                                   int N, int IC) {
    int cc = blockIdx.x * blockDim.x + threadIdx.x;
    if (cc < IC) {
        float invN = 1.0f / (float)N;
        float mean = sum[cc] * invN;
        float var = sumsq[cc] * invN - mean * mean;
        float sc = gamma[cc] * rsqrtf(var + BN_EPS);
        scale[cc] = sc;
        shift[cc] = beta[cc] - mean * sc;
    }
}

// ---------------- final: out = relu(bn2(h2) + x) ----------------

__global__ void final_kernel(const float* __restrict__ h2, const float* __restrict__ x,
                             const float* __restrict__ scale, const float* __restrict__ shift,
                             float* __restrict__ out, int total4, int C4) {
    int idx = blockIdx.x * blockDim.x + threadIdx.x;
    if (idx >= total4) return;
    int c4 = (idx % C4) * 4;
    float4 h = ((const float4*)h2)[idx];
    float4 xv = ((const float4*)x)[idx];
    float4 o;
    o.x = fmaxf(fmaf(h.x, scale[c4 + 0], shift[c4 + 0]) + xv.x, 0.f);
    o.y = fmaxf(fmaf(h.y, scale[c4 + 1], shift[c4 + 1]) + xv.y, 0.f);
    o.z = fmaxf(fmaf(h.z, scale[c4 + 2], shift[c4 + 2]) + xv.z, 0.f);
    o.w = fmaxf(fmaf(h.w, scale[c4 + 3], shift[c4 + 3]) + xv.w, 0.f);
    ((float4*)out)[idx] = o;
}

// ---------------- launch ----------------

extern "C" void kernel_launch(void* const* d_in, const int* in_sizes, int n_in,
                              void* d_out, int out_size, void* d_ws, size_t ws_size,
                              hipStream_t stream) {
    const float* x  = (const float*)d_in[0];
    const int*   es = (const int*)d_in[1];
    const float* W1 = (const float*)d_in[2];
    const float* g1 = (const float*)d_in[3];
    const float* b1 = (const float*)d_in[4];
    const float* W2 = (const float*)d_in[5];
    const float* g2 = (const float*)d_in[6];
    const float* b2 = (const float*)d_in[7];
    float* out = (float*)d_out;

    const int E  = in_sizes[1] / 2;
    const int IC = in_sizes[3];   // 512
    const int C  = in_sizes[7];   // 256
    const int N  = in_sizes[0] / C;

    const int* row = es;
    const int* col = es + E;

    // ---- workspace layout ----
    char* w = (char*)d_ws;
    size_t off = 0;
    auto alloc = [&](size_t bytes) -> void* {
        void* p = w + off;
        off = (off + bytes + 255) & ~(size_t)255;
        return p;
    };
    int*   cnt     = (int*)alloc((size_t)N * 4);
    float* dis     = (float*)alloc((size_t)N * 4);
    int*   rowptr  = (int*)alloc((size_t)(N + 1) * 4);
    int*   cursor  = (int*)alloc((size_t)N * 4);
    int*   adj     = (int*)alloc((size_t)E * 4);
    float* bnbuf   = (float*)alloc((size_t)(2 * IC + 2 * C) * 4);
    float* sum1    = bnbuf;
    float* sumsq1  = bnbuf + IC;
    float* sum2    = bnbuf + 2 * IC;
    float* sumsq2  = bnbuf + 2 * IC + C;
    float* scale1  = (float*)alloc((size_t)IC * 4);
    float* shift1  = (float*)alloc((size_t)IC * 4);
    float* scale2  = (float*)alloc((size_t)C * 4);
    float* shift2  = (float*)alloc((size_t)C * 4);
    ushort* xbf    = (ushort*)alloc((size_t)N * C * 2);
    ushort* W1bf   = (ushort*)alloc((size_t)IC * C * 2);
    ushort* W2bf   = (ushort*)alloc((size_t)IC * C * 2);
    // region1: xl1 (fp32 N*IC); later h1bf (bf16 N*IC) + xl2 (fp32 N*C)
    float* region1 = (float*)alloc((size_t)N * IC * 4);
    // region2: h1 (fp32 N*IC); later h2 (fp32 N*C)
    float* region2 = (float*)alloc((size_t)N * IC * 4);

    float*  xl1  = region1;
    ushort* h1bf = (ushort*)region1;
    float*  xl2  = (float*)((char*)region1 + (size_t)N * IC * 2);
    float*  h1   = region2;
    float*  h2   = region2;

    // ---- zero-init ----
    hipMemsetAsync(cnt, 0, (size_t)N * 4, stream);
    hipMemsetAsync(bnbuf, 0, (size_t)(2 * IC + 2 * C) * 4, stream);

    // ---- degree + CSR ----
    count_deg_kernel<<<(E + 255) / 256, 256, 0, stream>>>(col, cnt, E);
    dis_kernel<<<(N + 255) / 256, 256, 0, stream>>>(cnt, dis, N);
    scan_kernel<<<1, 1024, 0, stream>>>(cnt, rowptr, cursor, N);
    scatter_kernel<<<(E + 255) / 256, 256, 0, stream>>>(row, col, cursor, adj, E);

    // ---- bf16 conversions ----
    f2b_kernel<<<((N * C / 4) + 255) / 256, 256, 0, stream>>>(x, xbf, N * C / 4);
    f2b_kernel<<<((IC * C / 4) + 255) / 256, 256, 0, stream>>>(W1, W1bf, IC * C / 4);
    f2b_kernel<<<((IC * C / 4) + 255) / 256, 256, 0, stream>>>(W2, W2bf, IC * C / 4);

    // ---- layer 1: xl1 = x @ W1^T ----
    {
        dim3 grid(IC / 128, (N + 127) / 128);
        gemm_mfma_kernel<<<grid, 256, 0, stream>>>(xbf, W1bf, xl1, N, IC, C);
    }
    gather_kernel<2><<<N, 256, 0, stream>>>(xl1, rowptr, adj, dis, h1, IC);
    {
        int chunks = 512;
        int rpc = (N + chunks - 1) / chunks;
        bn_stats_kernel<<<chunks, 256, 0, stream>>>(h1, sum1, sumsq1, N, IC, rpc);
    }
    bn_finalize_kernel<<<(IC + 255) / 256, 256, 0, stream>>>(sum1, sumsq1, g1, b1, scale1, shift1, N, IC);

    // ---- BN1 + ReLU + cast (xl1 is dead; h1bf aliases region1 start) ----
    bn_apply_b_kernel<<<((N * IC / 4) + 255) / 256, 256, 0, stream>>>(
        h1, scale1, shift1, h1bf, N * IC / 4, IC / 4);

    // ---- layer 2: xl2 = relu(bn1(h1)) @ W2^T ----
    {
        dim3 grid(C / 128, (N + 127) / 128);
        gemm_mfma_kernel<<<grid, 256, 0, stream>>>(h1bf, W2bf, xl2, N, C, IC);
    }
    gather_kernel<1><<<N, 256, 0, stream>>>(xl2, rowptr, adj, dis, h2, C);
    {
        int chunks = 512;
        int rpc = (N + chunks - 1) / chunks;
        bn_stats_kernel<<<chunks, 256, 0, stream>>>(h2, sum2, sumsq2, N, C, rpc);
    }
    bn_finalize_kernel<<<(C + 255) / 256, 256, 0, stream>>>(sum2, sumsq2, g2, b2, scale2, shift2, N, C);

    // ---- epilogue: relu(bn2(h2) + x) ----
    {
        int total4 = (N * C) / 4;
        final_kernel<<<(total4 + 255) / 256, 256, 0, stream>>>(h2, x, scale2, shift2, out, total4, C / 4);
    }
}

// Round 4
// 265.118 us; speedup vs baseline: 1.5186x; 1.3156x over previous
//
#include <hip/hip_runtime.h>

#define BN_EPS 1e-5f

typedef __attribute__((ext_vector_type(8))) short short8;
typedef __attribute__((ext_vector_type(4))) float floatx4;

#define GLL(gp, lp)                                                            \
    __builtin_amdgcn_global_load_lds(                                          \
        (const __attribute__((address_space(1))) void*)(gp),                   \
        (__attribute__((address_space(3))) void*)(lp), 16, 0, 0)

__device__ inline unsigned short f2bf(float f) {
    unsigned int u = __float_as_uint(f);
    unsigned int r = (u + 0x7FFF + ((u >> 16) & 1)) >> 16;  // RNE
    return (unsigned short)r;
}

// ---------------- degree / CSR construction ----------------

__global__ void count_deg_kernel(const int* __restrict__ col, int* __restrict__ cnt, int E) {
    int e = blockIdx.x * blockDim.x + threadIdx.x;
    if (e < E) atomicAdd(&cnt[col[e]], 1);
}

__global__ void dis_kernel(const int* __restrict__ cnt, float* __restrict__ dis, int N) {
    int i = blockIdx.x * blockDim.x + threadIdx.x;
    if (i < N) dis[i] = rsqrtf((float)(cnt[i] + 1));   // +1 self loop; always > 0
}

__global__ __launch_bounds__(1024) void scan_kernel(const int* __restrict__ cnt,
                                                    int* __restrict__ rowptr,
                                                    int* __restrict__ cursor, int N) {
    __shared__ int sums[1024];
    int t = threadIdx.x;
    int per = (N + 1023) / 1024;
    int start = t * per;
    int local = 0;
    for (int i = 0; i < per; i++) {
        int idx = start + i;
        if (idx < N) local += cnt[idx];
    }
    sums[t] = local;
    __syncthreads();
    for (int off = 1; off < 1024; off <<= 1) {
        int v = (t >= off) ? sums[t - off] : 0;
        __syncthreads();
        sums[t] += v;
        __syncthreads();
    }
    int run = (t == 0) ? 0 : sums[t - 1];
    for (int i = 0; i < per; i++) {
        int idx = start + i;
        if (idx < N) {
            rowptr[idx] = run;
            cursor[idx] = run;
            run += cnt[idx];
        }
    }
    if (t == 0) rowptr[N] = sums[1023];
}

__global__ void scatter_kernel(const int* __restrict__ row, const int* __restrict__ col,
                               int* __restrict__ cursor, int* __restrict__ adj, int E) {
    int e = blockIdx.x * blockDim.x + threadIdx.x;
    if (e < E) {
        int pos = atomicAdd(&cursor[col[e]], 1);
        adj[pos] = row[e];
    }
}

// ---------------- fp32 -> bf16 conversion ----------------

__global__ void f2b_kernel(const float* __restrict__ in, ushort* __restrict__ out, int n4) {
    int i = blockIdx.x * blockDim.x + threadIdx.x;
    if (i < n4) {
        float4 v = ((const float4*)in)[i];
        ushort4 o;
        o.x = f2bf(v.x); o.y = f2bf(v.y); o.z = f2bf(v.z); o.w = f2bf(v.w);
        ((ushort4*)out)[i] = o;
    }
}

// BN+ReLU applied, then convert to bf16 (feeds GEMM2's A)
__global__ void bn_apply_b_kernel(const float* __restrict__ h,
                                  const float* __restrict__ scale,
                                  const float* __restrict__ shift,
                                  ushort* __restrict__ out, int n4, int IC4) {
    int i = blockIdx.x * blockDim.x + threadIdx.x;
    if (i >= n4) return;
    int c4 = (i & (IC4 - 1)) * 4;
    float4 v = ((const float4*)h)[i];
    ushort4 o;
    o.x = f2bf(fmaxf(fmaf(v.x, scale[c4 + 0], shift[c4 + 0]), 0.f));
    o.y = f2bf(fmaxf(fmaf(v.y, scale[c4 + 1], shift[c4 + 1]), 0.f));
    o.z = f2bf(fmaxf(fmaf(v.z, scale[c4 + 2], shift[c4 + 2]), 0.f));
    o.w = f2bf(fmaxf(fmaf(v.w, scale[c4 + 3], shift[c4 + 3]), 0.f));
    ((ushort4*)out)[i] = o;
}

// ---------------- MFMA GEMM: C[M,N] = A[M,K] @ B[N,K]^T (bf16 in, fp32 out) ---

__global__ __launch_bounds__(256) void gemm_mfma_kernel(
    const ushort* __restrict__ A, const ushort* __restrict__ B,
    float* __restrict__ C, int M, int N, int K) {
    __shared__ ushort As[128 * 32];
    __shared__ ushort Bs[128 * 32];
    int tid = threadIdx.x;
    int wave = tid >> 6;
    int lane = tid & 63;
    int quad = lane >> 4;
    int l15 = lane & 15;
    int m0 = blockIdx.y * 128;
    int n0 = blockIdx.x * 128;

    int srow = lane >> 2;        // row within 16-row chunk
    int skoff = (lane & 3) * 8;  // bf16-element offset within K-chunk

    floatx4 acc[4][4];
#pragma unroll
    for (int i = 0; i < 4; i++)
#pragma unroll
        for (int j = 0; j < 4; j++) acc[i][j] = (floatx4){0.f, 0.f, 0.f, 0.f};

    int wm = (wave & 1) * 64;
    int wn = (wave >> 1) * 64;

    for (int k0 = 0; k0 < K; k0 += 32) {
#pragma unroll
        for (int cc = 0; cc < 2; cc++) {
            int c = wave * 2 + cc;  // 16-row chunk index, 0..7
            int arow = m0 + c * 16 + srow;
            arow = min(arow, M - 1);
            const ushort* ga = A + (size_t)arow * K + k0 + skoff;
            GLL(ga, (char*)As + c * 1024);
            int brow = n0 + c * 16 + srow;
            const ushort* gb = B + (size_t)brow * K + k0 + skoff;
            GLL(gb, (char*)Bs + c * 1024);
        }
        __syncthreads();

        short8 af[4], bfr[4];
#pragma unroll
        for (int i = 0; i < 4; i++) {
            int r = wm + i * 16 + l15;
            af[i] = *(const short8*)(As + r * 32 + quad * 8);
        }
#pragma unroll
        for (int j = 0; j < 4; j++) {
            int r = wn + j * 16 + l15;
            bfr[j] = *(const short8*)(Bs + r * 32 + quad * 8);
        }
#pragma unroll
        for (int i = 0; i < 4; i++)
#pragma unroll
            for (int j = 0; j < 4; j++)
                acc[i][j] = __builtin_amdgcn_mfma_f32_16x16x32_bf16(af[i], bfr[j], acc[i][j], 0, 0, 0);
        __syncthreads();
    }

#pragma unroll
    for (int i = 0; i < 4; i++) {
#pragma unroll
        for (int r = 0; r < 4; r++) {
            int row = m0 + wm + i * 16 + quad * 4 + r;
            if (row < M) {
                float* cp = C + (size_t)row * N + n0 + wn + l15;
#pragma unroll
                for (int j = 0; j < 4; j++) cp[j * 16] = acc[i][j][r];
            }
        }
    }
}

// ---------------- gather (CSR segment-sum with sym norm) ----------------

template <int CPT> // channels per thread; IC = CPT*256
__global__ __launch_bounds__(256) void gather_kernel(
    const float* __restrict__ xl, const int* __restrict__ rowptr,
    const int* __restrict__ adj, const float* __restrict__ dis,
    float* __restrict__ h, int IC) {
    int v = blockIdx.x;
    float dv = dis[v];
    int c[CPT];
    float acc[CPT];
#pragma unroll
    for (int i = 0; i < CPT; i++) {
        c[i] = threadIdx.x + 256 * i;
        acc[i] = xl[(size_t)v * IC + c[i]] * dv * dv;
    }
    int e0 = rowptr[v], e1 = rowptr[v + 1];
    for (int e = e0; e < e1; e++) {
        int r = adj[e];
        float w = dis[r] * dv;
        const float* xr = xl + (size_t)r * IC;
#pragma unroll
        for (int i = 0; i < CPT; i++) acc[i] = fmaf(xr[c[i]], w, acc[i]);
    }
    float* hv = h + (size_t)v * IC;
#pragma unroll
    for (int i = 0; i < CPT; i++) hv[c[i]] = acc[i];
}

// ---------------- batchnorm stats: two-stage, no atomics ----------------
// Stage A: per-chunk partial sum/sumsq, channel-major output [IC][chunks].

__global__ __launch_bounds__(256) void bn_partial_kernel(
    const float* __restrict__ h, float* __restrict__ psum, float* __restrict__ psumsq,
    int N, int IC, int rows_per_chunk, int chunks) {
    int groups = IC >> 2;          // 128 (IC=512) or 64 (C=256)
    int rpi = 256 / groups;        // rows per iteration: 2 or 4
    int t = threadIdx.x;
    int g = t & (groups - 1);
    int ro = t / groups;
    int r0 = blockIdx.x * rows_per_chunk;
    int r1 = min(r0 + rows_per_chunk, N);

    float4 s = make_float4(0.f, 0.f, 0.f, 0.f);
    float4 q = make_float4(0.f, 0.f, 0.f, 0.f);
    for (int r = r0 + ro; r < r1; r += rpi) {
        float4 v = *(const float4*)(h + (size_t)r * IC + g * 4);
        s.x += v.x; s.y += v.y; s.z += v.z; s.w += v.w;
        q.x += v.x * v.x; q.y += v.y * v.y; q.z += v.z * v.z; q.w += v.w * v.w;
    }

    __shared__ float4 redS[256];
    __shared__ float4 redQ[256];
    redS[t] = s;
    redQ[t] = q;
    __syncthreads();
    if (ro == 0) {
        for (int i = 1; i < rpi; i++) {
            float4 o = redS[t + i * groups];
            s.x += o.x; s.y += o.y; s.z += o.z; s.w += o.w;
            float4 p = redQ[t + i * groups];
            q.x += p.x; q.y += p.y; q.z += p.z; q.w += p.w;
        }
        int k = blockIdx.x;
        psum[(size_t)(4 * g + 0) * chunks + k] = s.x;
        psum[(size_t)(4 * g + 1) * chunks + k] = s.y;
        psum[(size_t)(4 * g + 2) * chunks + k] = s.z;
        psum[(size_t)(4 * g + 3) * chunks + k] = s.w;
        psumsq[(size_t)(4 * g + 0) * chunks + k] = q.x;
        psumsq[(size_t)(4 * g + 1) * chunks + k] = q.y;
        psumsq[(size_t)(4 * g + 2) * chunks + k] = q.z;
        psumsq[(size_t)(4 * g + 3) * chunks + k] = q.w;
    }
}

// Stage B: one wave per channel; reduce partials, emit scale/shift.
__global__ __launch_bounds__(256) void bn_reduce_kernel(
    const float* __restrict__ psum, const float* __restrict__ psumsq,
    const float* __restrict__ gamma, const float* __restrict__ beta,
    float* __restrict__ scale, float* __restrict__ shift,
    int N, int chunks) {
    int wave = threadIdx.x >> 6;
    int lane = threadIdx.x & 63;
    int c = blockIdx.x * 4 + wave;
    float s = 0.f, q = 0.f;
    for (int k = lane; k < chunks; k += 64) {
        s += psum[(size_t)c * chunks + k];
        q += psumsq[(size_t)c * chunks + k];
    }
#pragma unroll
    for (int off = 32; off > 0; off >>= 1) {
        s += __shfl_down(s, off, 64);
        q += __shfl_down(q, off, 64);
    }
    if (lane == 0) {
        float invN = 1.0f / (float)N;
        float mean = s * invN;
        float var = q * invN - mean * mean;
        float sc = gamma[c] * rsqrtf(var + BN_EPS);
        scale[c] = sc;
        shift[c] = beta[c] - mean * sc;
    }
}

// ---------------- final: out = relu(bn2(h2) + x) ----------------

__global__ void final_kernel(const float* __restrict__ h2, const float* __restrict__ x,
                             const float* __restrict__ scale, const float* __restrict__ shift,
                             float* __restrict__ out, int total4, int C4) {
    int idx = blockIdx.x * blockDim.x + threadIdx.x;
    if (idx >= total4) return;
    int c4 = (idx % C4) * 4;
    float4 h = ((const float4*)h2)[idx];
    float4 xv = ((const float4*)x)[idx];
    float4 o;
    o.x = fmaxf(fmaf(h.x, scale[c4 + 0], shift[c4 + 0]) + xv.x, 0.f);
    o.y = fmaxf(fmaf(h.y, scale[c4 + 1], shift[c4 + 1]) + xv.y, 0.f);
    o.z = fmaxf(fmaf(h.z, scale[c4 + 2], shift[c4 + 2]) + xv.z, 0.f);
    o.w = fmaxf(fmaf(h.w, scale[c4 + 3], shift[c4 + 3]) + xv.w, 0.f);
    ((float4*)out)[idx] = o;
}

// ---------------- launch ----------------

extern "C" void kernel_launch(void* const* d_in, const int* in_sizes, int n_in,
                              void* d_out, int out_size, void* d_ws, size_t ws_size,
                              hipStream_t stream) {
    const float* x  = (const float*)d_in[0];
    const int*   es = (const int*)d_in[1];
    const float* W1 = (const float*)d_in[2];
    const float* g1 = (const float*)d_in[3];
    const float* b1 = (const float*)d_in[4];
    const float* W2 = (const float*)d_in[5];
    const float* g2 = (const float*)d_in[6];
    const float* b2 = (const float*)d_in[7];
    float* out = (float*)d_out;

    const int E  = in_sizes[1] / 2;
    const int IC = in_sizes[3];   // 512
    const int C  = in_sizes[7];   // 256
    const int N  = in_sizes[0] / C;
    const int CHUNKS = 512;

    const int* row = es;
    const int* col = es + E;

    // ---- workspace layout ----
    char* w = (char*)d_ws;
    size_t off = 0;
    auto alloc = [&](size_t bytes) -> void* {
        void* p = w + off;
        off = (off + bytes + 255) & ~(size_t)255;
        return p;
    };
    int*   cnt     = (int*)alloc((size_t)N * 4);
    float* dis     = (float*)alloc((size_t)N * 4);
    int*   rowptr  = (int*)alloc((size_t)(N + 1) * 4);
    int*   cursor  = (int*)alloc((size_t)N * 4);
    int*   adj     = (int*)alloc((size_t)E * 4);
    float* psum    = (float*)alloc((size_t)IC * CHUNKS * 4);  // reused by both layers
    float* psumsq  = (float*)alloc((size_t)IC * CHUNKS * 4);
    float* scale1  = (float*)alloc((size_t)IC * 4);
    float* shift1  = (float*)alloc((size_t)IC * 4);
    float* scale2  = (float*)alloc((size_t)C * 4);
    float* shift2  = (float*)alloc((size_t)C * 4);
    ushort* xbf    = (ushort*)alloc((size_t)N * C * 2);
    ushort* W1bf   = (ushort*)alloc((size_t)IC * C * 2);
    ushort* W2bf   = (ushort*)alloc((size_t)IC * C * 2);
    // region1: xl1 (fp32 N*IC); later h1bf (bf16 N*IC) + xl2 (fp32 N*C)
    float* region1 = (float*)alloc((size_t)N * IC * 4);
    // region2: h1 (fp32 N*IC); later h2 (fp32 N*C)
    float* region2 = (float*)alloc((size_t)N * IC * 4);

    float*  xl1  = region1;
    ushort* h1bf = (ushort*)region1;
    float*  xl2  = (float*)((char*)region1 + (size_t)N * IC * 2);
    float*  h1   = region2;
    float*  h2   = region2;

    // ---- zero-init ----
    hipMemsetAsync(cnt, 0, (size_t)N * 4, stream);

    // ---- degree + CSR ----
    count_deg_kernel<<<(E + 255) / 256, 256, 0, stream>>>(col, cnt, E);
    dis_kernel<<<(N + 255) / 256, 256, 0, stream>>>(cnt, dis, N);
    scan_kernel<<<1, 1024, 0, stream>>>(cnt, rowptr, cursor, N);
    scatter_kernel<<<(E + 255) / 256, 256, 0, stream>>>(row, col, cursor, adj, E);

    // ---- bf16 conversions ----
    f2b_kernel<<<((N * C / 4) + 255) / 256, 256, 0, stream>>>(x, xbf, N * C / 4);
    f2b_kernel<<<((IC * C / 4) + 255) / 256, 256, 0, stream>>>(W1, W1bf, IC * C / 4);
    f2b_kernel<<<((IC * C / 4) + 255) / 256, 256, 0, stream>>>(W2, W2bf, IC * C / 4);

    // ---- layer 1: xl1 = x @ W1^T ----
    {
        dim3 grid(IC / 128, (N + 127) / 128);
        gemm_mfma_kernel<<<grid, 256, 0, stream>>>(xbf, W1bf, xl1, N, IC, C);
    }
    gather_kernel<2><<<N, 256, 0, stream>>>(xl1, rowptr, adj, dis, h1, IC);
    {
        int rpc = (N + CHUNKS - 1) / CHUNKS;
        bn_partial_kernel<<<CHUNKS, 256, 0, stream>>>(h1, psum, psumsq, N, IC, rpc, CHUNKS);
        bn_reduce_kernel<<<IC / 4, 256, 0, stream>>>(psum, psumsq, g1, b1, scale1, shift1, N, CHUNKS);
    }

    // ---- BN1 + ReLU + cast (xl1 is dead; h1bf aliases region1 start) ----
    bn_apply_b_kernel<<<((N * IC / 4) + 255) / 256, 256, 0, stream>>>(
        h1, scale1, shift1, h1bf, N * IC / 4, IC / 4);

    // ---- layer 2: xl2 = relu(bn1(h1)) @ W2^T ----
    {
        dim3 grid(C / 128, (N + 127) / 128);
        gemm_mfma_kernel<<<grid, 256, 0, stream>>>(h1bf, W2bf, xl2, N, C, IC);
    }
    gather_kernel<1><<<N, 256, 0, stream>>>(xl2, rowptr, adj, dis, h2, C);
    {
        int rpc = (N + CHUNKS - 1) / CHUNKS;
        bn_partial_kernel<<<CHUNKS, 256, 0, stream>>>(h2, psum, psumsq, N, C, rpc, CHUNKS);
        bn_reduce_kernel<<<C / 4, 256, 0, stream>>>(psum, psumsq, g2, b2, scale2, shift2, N, CHUNKS);
    }

    // ---- epilogue: relu(bn2(h2) + x) ----
    {
        int total4 = (N * C) / 4;
        final_kernel<<<(total4 + 255) / 256, 256, 0, stream>>>(h2, x, scale2, shift2, out, total4, C / 4);
    }
}

// Round 5
// 234.443 us; speedup vs baseline: 1.7173x; 1.1308x over previous
//
#include <hip/hip_runtime.h>

#define BN_EPS 1e-5f

typedef __attribute__((ext_vector_type(8))) short short8;
typedef __attribute__((ext_vector_type(4))) float floatx4;

#define GLL(gp, lp)                                                            \
    __builtin_amdgcn_global_load_lds(                                          \
        (const __attribute__((address_space(1))) void*)(gp),                   \
        (__attribute__((address_space(3))) void*)(lp), 16, 0, 0)

__device__ inline unsigned short f2bf(float f) {
    unsigned int u = __float_as_uint(f);
    unsigned int r = (u + 0x7FFF + ((u >> 16) & 1)) >> 16;  // RNE
    return (unsigned short)r;
}

__device__ inline float bf2f(unsigned short u) {
    return __uint_as_float(((unsigned int)u) << 16);
}

// ---------------- degree / CSR construction ----------------

__global__ void count_deg_kernel(const int* __restrict__ col, int* __restrict__ cnt, int E) {
    int e = blockIdx.x * blockDim.x + threadIdx.x;
    if (e < E) atomicAdd(&cnt[col[e]], 1);
}

__global__ void dis_kernel(const int* __restrict__ cnt, float* __restrict__ dis, int N) {
    int i = blockIdx.x * blockDim.x + threadIdx.x;
    if (i < N) dis[i] = rsqrtf((float)(cnt[i] + 1));   // +1 self loop; always > 0
}

__global__ __launch_bounds__(1024) void scan_kernel(const int* __restrict__ cnt,
                                                    int* __restrict__ rowptr,
                                                    int* __restrict__ cursor, int N) {
    __shared__ int sums[1024];
    int t = threadIdx.x;
    int per = (N + 1023) / 1024;
    int start = t * per;
    int local = 0;
    for (int i = 0; i < per; i++) {
        int idx = start + i;
        if (idx < N) local += cnt[idx];
    }
    sums[t] = local;
    __syncthreads();
    for (int off = 1; off < 1024; off <<= 1) {
        int v = (t >= off) ? sums[t - off] : 0;
        __syncthreads();
        sums[t] += v;
        __syncthreads();
    }
    int run = (t == 0) ? 0 : sums[t - 1];
    for (int i = 0; i < per; i++) {
        int idx = start + i;
        if (idx < N) {
            rowptr[idx] = run;
            cursor[idx] = run;
            run += cnt[idx];
        }
    }
    if (t == 0) rowptr[N] = sums[1023];
}

__global__ void scatter_kernel(const int* __restrict__ row, const int* __restrict__ col,
                               int* __restrict__ cursor, int* __restrict__ adj, int E) {
    int e = blockIdx.x * blockDim.x + threadIdx.x;
    if (e < E) {
        int pos = atomicAdd(&cursor[col[e]], 1);
        adj[pos] = row[e];
    }
}

// ---------------- fp32 -> bf16 conversion ----------------

__global__ void f2b_kernel(const float* __restrict__ in, ushort* __restrict__ out, int n4) {
    int i = blockIdx.x * blockDim.x + threadIdx.x;
    if (i < n4) {
        float4 v = ((const float4*)in)[i];
        ushort4 o;
        o.x = f2bf(v.x); o.y = f2bf(v.y); o.z = f2bf(v.z); o.w = f2bf(v.w);
        ((ushort4*)out)[i] = o;
    }
}

// BN+ReLU applied, then convert to bf16 (feeds GEMM2's A)
__global__ void bn_apply_b_kernel(const float* __restrict__ h,
                                  const float* __restrict__ scale,
                                  const float* __restrict__ shift,
                                  ushort* __restrict__ out, int n4, int IC4) {
    int i = blockIdx.x * blockDim.x + threadIdx.x;
    if (i >= n4) return;
    int c4 = (i & (IC4 - 1)) * 4;
    float4 v = ((const float4*)h)[i];
    ushort4 o;
    o.x = f2bf(fmaxf(fmaf(v.x, scale[c4 + 0], shift[c4 + 0]), 0.f));
    o.y = f2bf(fmaxf(fmaf(v.y, scale[c4 + 1], shift[c4 + 1]), 0.f));
    o.z = f2bf(fmaxf(fmaf(v.z, scale[c4 + 2], shift[c4 + 2]), 0.f));
    o.w = f2bf(fmaxf(fmaf(v.w, scale[c4 + 3], shift[c4 + 3]), 0.f));
    ((ushort4*)out)[i] = o;
}

// ---------------- MFMA GEMM: C[M,N] = A[M,K] @ B[N,K]^T (bf16 in) ----------

template <bool OUT_BF16>
__global__ __launch_bounds__(256) void gemm_mfma_kernel(
    const ushort* __restrict__ A, const ushort* __restrict__ B,
    void* __restrict__ Cout, int M, int N, int K) {
    __shared__ ushort As[128 * 32];
    __shared__ ushort Bs[128 * 32];
    int tid = threadIdx.x;
    int wave = tid >> 6;
    int lane = tid & 63;
    int quad = lane >> 4;
    int l15 = lane & 15;
    int m0 = blockIdx.y * 128;
    int n0 = blockIdx.x * 128;

    int srow = lane >> 2;        // row within 16-row chunk
    int skoff = (lane & 3) * 8;  // bf16-element offset within K-chunk

    floatx4 acc[4][4];
#pragma unroll
    for (int i = 0; i < 4; i++)
#pragma unroll
        for (int j = 0; j < 4; j++) acc[i][j] = (floatx4){0.f, 0.f, 0.f, 0.f};

    int wm = (wave & 1) * 64;
    int wn = (wave >> 1) * 64;

    for (int k0 = 0; k0 < K; k0 += 32) {
#pragma unroll
        for (int cc = 0; cc < 2; cc++) {
            int c = wave * 2 + cc;  // 16-row chunk index, 0..7
            int arow = m0 + c * 16 + srow;
            arow = min(arow, M - 1);
            const ushort* ga = A + (size_t)arow * K + k0 + skoff;
            GLL(ga, (char*)As + c * 1024);
            int brow = n0 + c * 16 + srow;
            const ushort* gb = B + (size_t)brow * K + k0 + skoff;
            GLL(gb, (char*)Bs + c * 1024);
        }
        __syncthreads();

        short8 af[4], bfr[4];
#pragma unroll
        for (int i = 0; i < 4; i++) {
            int r = wm + i * 16 + l15;
            af[i] = *(const short8*)(As + r * 32 + quad * 8);
        }
#pragma unroll
        for (int j = 0; j < 4; j++) {
            int r = wn + j * 16 + l15;
            bfr[j] = *(const short8*)(Bs + r * 32 + quad * 8);
        }
#pragma unroll
        for (int i = 0; i < 4; i++)
#pragma unroll
            for (int j = 0; j < 4; j++)
                acc[i][j] = __builtin_amdgcn_mfma_f32_16x16x32_bf16(af[i], bfr[j], acc[i][j], 0, 0, 0);
        __syncthreads();
    }

#pragma unroll
    for (int i = 0; i < 4; i++) {
#pragma unroll
        for (int r = 0; r < 4; r++) {
            int row = m0 + wm + i * 16 + quad * 4 + r;
            if (row < M) {
                if (OUT_BF16) {
                    ushort* cp = (ushort*)Cout + (size_t)row * N + n0 + wn + l15;
#pragma unroll
                    for (int j = 0; j < 4; j++) cp[j * 16] = f2bf(acc[i][j][r]);
                } else {
                    float* cp = (float*)Cout + (size_t)row * N + n0 + wn + l15;
#pragma unroll
                    for (int j = 0; j < 4; j++) cp[j * 16] = acc[i][j][r];
                }
            }
        }
    }
}

// ---------------- bf16 gather, C=256 channels ----------------
// h[v][c] = xl[v][c]*dis[v]^2 + sum_{r in adj(v)} xl[r][c]*dis[r]*dis[v]
// One block per node; wave w handles edges e0+w, e0+w+4, ...; 64 lanes x ushort4
// cover 256 channels. LDS cross-wave reduction; fp32 accumulate throughout.

template <bool OUT_BF16>
__global__ __launch_bounds__(256) void gather_bf_kernel(
    const ushort* __restrict__ xl,   // [N, 256] bf16
    const int* __restrict__ rowptr, const int* __restrict__ adj,
    const float* __restrict__ dis,
    void* __restrict__ h) {          // [N, 256] bf16 or fp32
    int v = blockIdx.x;
    int wave = threadIdx.x >> 6;
    int lane = threadIdx.x & 63;
    float dv = dis[v];

    float acc[4] = {0.f, 0.f, 0.f, 0.f};
    int e0 = rowptr[v], e1 = rowptr[v + 1];
    for (int e = e0 + wave; e < e1; e += 4) {
        int r = adj[e];
        float wgt = dis[r] * dv;
        ushort4 u = ((const ushort4*)xl)[(size_t)r * 64 + lane];
        acc[0] = fmaf(bf2f(u.x), wgt, acc[0]);
        acc[1] = fmaf(bf2f(u.y), wgt, acc[1]);
        acc[2] = fmaf(bf2f(u.z), wgt, acc[2]);
        acc[3] = fmaf(bf2f(u.w), wgt, acc[3]);
    }

    __shared__ float4 red[4][64];
    red[wave][lane] = make_float4(acc[0], acc[1], acc[2], acc[3]);
    __syncthreads();
    if (wave == 0) {
        float4 s = red[0][lane];
        float4 b = red[1][lane];
        float4 c = red[2][lane];
        float4 d = red[3][lane];
        s.x += b.x + c.x + d.x;
        s.y += b.y + c.y + d.y;
        s.z += b.z + c.z + d.z;
        s.w += b.w + c.w + d.w;
        ushort4 u = ((const ushort4*)xl)[(size_t)v * 64 + lane];
        float w2 = dv * dv;
        s.x = fmaf(bf2f(u.x), w2, s.x);
        s.y = fmaf(bf2f(u.y), w2, s.y);
        s.z = fmaf(bf2f(u.z), w2, s.z);
        s.w = fmaf(bf2f(u.w), w2, s.w);
        if (OUT_BF16) {
            ushort4 o;
            o.x = f2bf(s.x); o.y = f2bf(s.y); o.z = f2bf(s.z); o.w = f2bf(s.w);
            ((ushort4*)h)[(size_t)v * 64 + lane] = o;
        } else {
            ((float4*)h)[(size_t)v * 64 + lane] = s;
        }
    }
}

// ---------------- batchnorm stats: two-stage, no atomics ----------------

__global__ __launch_bounds__(256) void bn_partial_kernel(
    const float* __restrict__ h, float* __restrict__ psum, float* __restrict__ psumsq,
    int N, int IC, int rows_per_chunk, int chunks) {
    int groups = IC >> 2;          // 128 (IC=512) or 64 (C=256)
    int rpi = 256 / groups;        // rows per iteration: 2 or 4
    int t = threadIdx.x;
    int g = t & (groups - 1);
    int ro = t / groups;
    int r0 = blockIdx.x * rows_per_chunk;
    int r1 = min(r0 + rows_per_chunk, N);

    float4 s = make_float4(0.f, 0.f, 0.f, 0.f);
    float4 q = make_float4(0.f, 0.f, 0.f, 0.f);
    for (int r = r0 + ro; r < r1; r += rpi) {
        float4 v = *(const float4*)(h + (size_t)r * IC + g * 4);
        s.x += v.x; s.y += v.y; s.z += v.z; s.w += v.w;
        q.x += v.x * v.x; q.y += v.y * v.y; q.z += v.z * v.z; q.w += v.w * v.w;
    }

    __shared__ float4 redS[256];
    __shared__ float4 redQ[256];
    redS[t] = s;
    redQ[t] = q;
    __syncthreads();
    if (ro == 0) {
        for (int i = 1; i < rpi; i++) {
            float4 o = redS[t + i * groups];
            s.x += o.x; s.y += o.y; s.z += o.z; s.w += o.w;
            float4 p = redQ[t + i * groups];
            q.x += p.x; q.y += p.y; q.z += p.z; q.w += p.w;
        }
        int k = blockIdx.x;
        psum[(size_t)(4 * g + 0) * chunks + k] = s.x;
        psum[(size_t)(4 * g + 1) * chunks + k] = s.y;
        psum[(size_t)(4 * g + 2) * chunks + k] = s.z;
        psum[(size_t)(4 * g + 3) * chunks + k] = s.w;
        psumsq[(size_t)(4 * g + 0) * chunks + k] = q.x;
        psumsq[(size_t)(4 * g + 1) * chunks + k] = q.y;
        psumsq[(size_t)(4 * g + 2) * chunks + k] = q.z;
        psumsq[(size_t)(4 * g + 3) * chunks + k] = q.w;
    }
}

__global__ __launch_bounds__(256) void bn_reduce_kernel(
    const float* __restrict__ psum, const float* __restrict__ psumsq,
    const float* __restrict__ gamma, const float* __restrict__ beta,
    float* __restrict__ scale, float* __restrict__ shift,
    int N, int chunks) {
    int wave = threadIdx.x >> 6;
    int lane = threadIdx.x & 63;
    int c = blockIdx.x * 4 + wave;
    float s = 0.f, q = 0.f;
    for (int k = lane; k < chunks; k += 64) {
        s += psum[(size_t)c * chunks + k];
        q += psumsq[(size_t)c * chunks + k];
    }
#pragma unroll
    for (int off = 32; off > 0; off >>= 1) {
        s += __shfl_down(s, off, 64);
        q += __shfl_down(q, off, 64);
    }
    if (lane == 0) {
        float invN = 1.0f / (float)N;
        float mean = s * invN;
        float var = q * invN - mean * mean;
        float sc = gamma[c] * rsqrtf(var + BN_EPS);
        scale[c] = sc;
        shift[c] = beta[c] - mean * sc;
    }
}

// ---------------- final: out = relu(bn2(h2) + x) ----------------

__global__ void final_kernel(const float* __restrict__ h2, const float* __restrict__ x,
                             const float* __restrict__ scale, const float* __restrict__ shift,
                             float* __restrict__ out, int total4, int C4) {
    int idx = blockIdx.x * blockDim.x + threadIdx.x;
    if (idx >= total4) return;
    int c4 = (idx % C4) * 4;
    float4 h = ((const float4*)h2)[idx];
    float4 xv = ((const float4*)x)[idx];
    float4 o;
    o.x = fmaxf(fmaf(h.x, scale[c4 + 0], shift[c4 + 0]) + xv.x, 0.f);
    o.y = fmaxf(fmaf(h.y, scale[c4 + 1], shift[c4 + 1]) + xv.y, 0.f);
    o.z = fmaxf(fmaf(h.z, scale[c4 + 2], shift[c4 + 2]) + xv.z, 0.f);
    o.w = fmaxf(fmaf(h.w, scale[c4 + 3], shift[c4 + 3]) + xv.w, 0.f);
    ((float4*)out)[idx] = o;
}

// ---------------- launch ----------------

extern "C" void kernel_launch(void* const* d_in, const int* in_sizes, int n_in,
                              void* d_out, int out_size, void* d_ws, size_t ws_size,
                              hipStream_t stream) {
    const float* x  = (const float*)d_in[0];
    const int*   es = (const int*)d_in[1];
    const float* W1 = (const float*)d_in[2];
    const float* g1 = (const float*)d_in[3];
    const float* b1 = (const float*)d_in[4];
    const float* W2 = (const float*)d_in[5];
    const float* g2 = (const float*)d_in[6];
    const float* b2 = (const float*)d_in[7];
    float* out = (float*)d_out;

    const int E  = in_sizes[1] / 2;
    const int IC = in_sizes[3];   // 512
    const int C  = in_sizes[7];   // 256
    const int N  = in_sizes[0] / C;
    const int CHUNKS = 512;

    const int* row = es;
    const int* col = es + E;

    // ---- workspace layout ----
    char* w = (char*)d_ws;
    size_t off = 0;
    auto alloc = [&](size_t bytes) -> void* {
        void* p = w + off;
        off = (off + bytes + 255) & ~(size_t)255;
        return p;
    };
    int*   cnt     = (int*)alloc((size_t)N * 4);
    float* dis     = (float*)alloc((size_t)N * 4);
    int*   rowptr  = (int*)alloc((size_t)(N + 1) * 4);
    int*   cursor  = (int*)alloc((size_t)N * 4);
    int*   adj     = (int*)alloc((size_t)E * 4);
    float* psum    = (float*)alloc((size_t)IC * CHUNKS * 4);  // reused by both layers
    float* psumsq  = (float*)alloc((size_t)IC * CHUNKS * 4);
    float* scale1  = (float*)alloc((size_t)IC * 4);
    float* shift1  = (float*)alloc((size_t)IC * 4);
    float* scale2  = (float*)alloc((size_t)C * 4);
    float* shift2  = (float*)alloc((size_t)C * 4);
    ushort* xbf    = (ushort*)alloc((size_t)N * C * 2);       // x in bf16
    ushort* W1bf   = (ushort*)alloc((size_t)IC * C * 2);
    ushort* W2bf   = (ushort*)alloc((size_t)IC * C * 2);
    ushort* g1x    = (ushort*)alloc((size_t)N * C * 2);       // gather(x) bf16
    float*  h1     = (float*)alloc((size_t)N * IC * 4);       // GEMM1 out fp32
    ushort* h1bf   = (ushort*)alloc((size_t)N * IC * 2);      // bn1+relu bf16
    ushort* xl2bf  = (ushort*)alloc((size_t)N * C * 2);       // GEMM2 out bf16
    float*  h2     = (float*)alloc((size_t)N * C * 4);        // gather2 out fp32

    // ---- zero-init ----
    hipMemsetAsync(cnt, 0, (size_t)N * 4, stream);

    // ---- degree + CSR ----
    count_deg_kernel<<<(E + 255) / 256, 256, 0, stream>>>(col, cnt, E);
    dis_kernel<<<(N + 255) / 256, 256, 0, stream>>>(cnt, dis, N);
    scan_kernel<<<1, 1024, 0, stream>>>(cnt, rowptr, cursor, N);
    scatter_kernel<<<(E + 255) / 256, 256, 0, stream>>>(row, col, cursor, adj, E);

    // ---- bf16 conversions ----
    f2b_kernel<<<((N * C / 4) + 255) / 256, 256, 0, stream>>>(x, xbf, N * C / 4);
    f2b_kernel<<<((IC * C / 4) + 255) / 256, 256, 0, stream>>>(W1, W1bf, IC * C / 4);
    f2b_kernel<<<((IC * C / 4) + 255) / 256, 256, 0, stream>>>(W2, W2bf, IC * C / 4);

    // ---- layer 1: aggregate-first.  g1x = A_norm(x);  h1 = g1x @ W1^T ----
    gather_bf_kernel<true><<<N, 256, 0, stream>>>(xbf, rowptr, adj, dis, g1x);
    {
        dim3 grid(IC / 128, (N + 127) / 128);
        gemm_mfma_kernel<false><<<grid, 256, 0, stream>>>(g1x, W1bf, h1, N, IC, C);
    }
    {
        int rpc = (N + CHUNKS - 1) / CHUNKS;
        bn_partial_kernel<<<CHUNKS, 256, 0, stream>>>(h1, psum, psumsq, N, IC, rpc, CHUNKS);
        bn_reduce_kernel<<<IC / 4, 256, 0, stream>>>(psum, psumsq, g1, b1, scale1, shift1, N, CHUNKS);
    }

    // ---- BN1 + ReLU + cast ----
    bn_apply_b_kernel<<<((N * IC / 4) + 255) / 256, 256, 0, stream>>>(
        h1, scale1, shift1, h1bf, N * IC / 4, IC / 4);

    // ---- layer 2: xl2 = relu(bn1(h1)) @ W2^T (bf16 out); h2 = A_norm(xl2) ----
    {
        dim3 grid(C / 128, (N + 127) / 128);
        gemm_mfma_kernel<true><<<grid, 256, 0, stream>>>(h1bf, W2bf, xl2bf, N, C, IC);
    }
    gather_bf_kernel<false><<<N, 256, 0, stream>>>(xl2bf, rowptr, adj, dis, h2);
    {
        int rpc = (N + CHUNKS - 1) / CHUNKS;
        bn_partial_kernel<<<CHUNKS, 256, 0, stream>>>(h2, psum, psumsq, N, C, rpc, CHUNKS);
        bn_reduce_kernel<<<C / 4, 256, 0, stream>>>(psum, psumsq, g2, b2, scale2, shift2, N, CHUNKS);
    }

    // ---- epilogue: relu(bn2(h2) + x) ----
    {
        int total4 = (N * C) / 4;
        final_kernel<<<(total4 + 255) / 256, 256, 0, stream>>>(h2, x, scale2, shift2, out, total4, C / 4);
    }
}